// Round 16
// baseline (105.454 us; speedup 1.0000x reference)
//
#include <hip/hip_runtime.h>

// Packed-sequence LSTM (B=4096, T=512, D=18, H=8) + Linear(8->1) head.
//
// R16: 8-sequence blocks -> 1 wave/SIMD. 512 blocks x 2 waves = 1024 waves
// on 1024 SIMDs (R14's 4-seq blocks forced 2 waves/SIMD; measured window
// wall ~= SUM of both waves' issue). Components reused from proven rounds:
//  - consumer lane (s=w>>3, j=w&7) owns ALL 4 gates of unit j, seq s: cell
//    update lane-local, no ror:8 exchange, no weight calibration needed.
//    h-broadcast = 8 x __shfl within the 8-lane group ((w&56)|r - R1's
//    correctness-proven pattern).
//  - producer writes all-4-gate pre-activations as v4f into XG
//    (v2f-over-gates with scalar-x splat: no horizontal folds).
//  - DMA lane maps = R7's proven patterns, duplicated per seq-half:
//    18 ops/chunk. vmcnt(36)/window: at iter-I wait, outstanding = 72
//    (chunks {2I+2..2I+5}); retiring the oldest 36 = {2I+2,2I+3}, DMA'd
//    one window (~5000cy) ago >> 900cy HBM. Producer has NO stores ->
//    counts exact. Prologue: 4 chunks (72 ops), vmcnt(36) -> {0,1} ready.
//  - 16-step windows, raw s_barrier (+sched_barrier fences), first xg read
//    of each window AFTER the barrier (R12-proven; in-window prefetch 1
//    step ahead, stops at k=15).
//  - length-balanced swizzle: block pairs {q, 511-q} -> per-CU work const.
// LDS 50KB -> 2 blocks/CU -> 4 waves/CU = 1 wave/SIMD (the point).
// Ring safety (as R12, re-checked): XG writes {2I+2,2I+3}&3 disjoint from
// reads {2I,2I+1}&3; Aring/Bring slots being DMA'd were last read by the
// SAME wave one iter earlier (lgkm-drained) -> no cross-wave race.

namespace {

constexpr int NT = 512;
constexpr int ND = 18;
constexpr float LOG2E = 1.4426950408889634f;

typedef float v2f __attribute__((ext_vector_type(2)));
typedef float v4f __attribute__((ext_vector_type(4)));

__device__ __forceinline__ void gload_lds(const void* g, void* l) {
    __builtin_amdgcn_global_load_lds(
        (const __attribute__((address_space(1))) void*)g,
        (__attribute__((address_space(3))) void*)l, 4, 0, 0);
}

__global__ __launch_bounds__(128, 1) void lstm_pc8(
    const float* __restrict__ x, const int* __restrict__ lengths,
    const float* __restrict__ W_ih, const float* __restrict__ W_hh,
    const float* __restrict__ b_ih, const float* __restrict__ b_hh,
    const float* __restrict__ W_lin, const float* __restrict__ b_lin,
    float* __restrict__ out)
{
    // Aring: 32 row slots (row r -> slot r&31), [seq0..7][elem0..15]. 16KB
    // Bring: 4 chunk bufs, [seq-half][row][seq-in-half][elem16..17].   2KB
    // XG:    4 chunk bufs, [step][seq][j] of v4f (i,f,g,o pre-acts).  32KB
    __shared__ __align__(16) float Aring[32][8][16];
    __shared__ __align__(16) float Bring[4][2][8][4][2];
    __shared__ __align__(16) v4f   XG[4][8][8][8];

    // balanced swizzle over 512 blocks: CU slot q hosts groups {q, 511-q}
    const int q_ = (int)blockIdx.x & 255;
    const int g  = ((int)blockIdx.x >> 8) ? (511 - q_) : q_;

    const int tid = (int)threadIdx.x;
    const int wav = tid >> 6;           // 0 = consumer, 1 = producer
    const int w   = tid & 63;
    const int s   = w >> 3;             // seq within block (0..7)
    const int j   = w & 7;              // hidden unit
    const int lenmax = lengths[g * 8];  // sorted desc -> block max
    const int nwin = (lenmax + 15) >> 4;

    if (wav == 1) {
        // ============================ PRODUCER ============================
        // per-lane weights for unit j, all 4 gates as v2f pairs (i,f),(g,o)
        v2f wxIF[ND], wxGO[ND];
#pragma unroll
        for (int k = 0; k < ND; ++k) {
            wxIF[k] = v2f{W_ih[j * ND + k],        W_ih[(8 + j) * ND + k]};
            wxGO[k] = v2f{W_ih[(16 + j) * ND + k], W_ih[(24 + j) * ND + k]};
        }
        const v2f bIF = v2f{b_ih[j] + b_hh[j],           b_ih[8 + j] + b_hh[8 + j]};
        const v2f bGO = v2f{b_ih[16 + j] + b_hh[16 + j], b_ih[24 + j] + b_hh[24 + j]};

        // DMA lane maps (R7-proven, per seq-half):
        // A-op: seq = h*4 + (w>>4), elem = w&15 (row uniform per op)
        // B-op: row = w>>3, seq = h*4 + ((w>>1)&3), elem = 16 + (w&1)
        const char* xc = (const char*)x;
        const char* pA1 = xc + (size_t)((((unsigned)(g * 8 + (w >> 4)) * (NT * ND))
                                        + (unsigned)(w & 15)) * 4u);
        const char* pA2 = xc + (size_t)((((unsigned)(g * 8 + 4 + (w >> 4)) * (NT * ND))
                                        + (unsigned)(w & 15)) * 4u);
        const char* pB1 = xc + (size_t)((((unsigned)(g * 8 + ((w >> 1) & 3)) * (NT * ND))
                                        + 16u + (unsigned)(w & 1)) * 4u);
        const char* pB2 = xc + (size_t)((((unsigned)(g * 8 + 4 + ((w >> 1) & 3)) * (NT * ND))
                                        + 16u + (unsigned)(w & 1)) * 4u);
        const unsigned rB0 = (unsigned)(w >> 3);

        auto dma_chunk = [&](int dd) {            // 18 vmem ops
            const int r0 = dd * 8;
#pragma unroll
            for (int k = 0; k < 8; ++k) {
                const int rr = (r0 + k < NT) ? (r0 + k) : (NT - 1);
                gload_lds(pA1 + (unsigned)rr * 72u, &Aring[(r0 + k) & 31][0][0]);
                gload_lds(pA2 + (unsigned)rr * 72u, &Aring[(r0 + k) & 31][4][0]);
            }
            unsigned rb = (unsigned)r0 + rB0;
            rb = (rb < (unsigned)NT) ? rb : (unsigned)(NT - 1);
            gload_lds(pB1 + rb * 72u, &Bring[dd & 3][0][0][0][0]);
            gload_lds(pB2 + rb * 72u, &Bring[dd & 3][1][0][0][0]);
        };

        // produce chunk cc: lane (s,j) computes 4 gate pre-acts per step
        auto produce_chunk = [&](int cc) {
            const int s0 = (cc * 8) & 31;
            const int bf = cc & 3;
#pragma unroll
            for (int k = 0; k < 8; ++k) {
                const v4f* ap = (const v4f*)&Aring[s0 + k][s][0];
                const v4f q0 = ap[0], q1 = ap[1], q2 = ap[2], q3 = ap[3];
                const v2f bt = *(const v2f*)&Bring[bf][s >> 2][k][s & 3][0];
                v2f aIF = bIF, aGO = bGO;
                aIF = q0.x * wxIF[0]  + aIF;  aGO = q0.x * wxGO[0]  + aGO;
                aIF = q0.y * wxIF[1]  + aIF;  aGO = q0.y * wxGO[1]  + aGO;
                aIF = q0.z * wxIF[2]  + aIF;  aGO = q0.z * wxGO[2]  + aGO;
                aIF = q0.w * wxIF[3]  + aIF;  aGO = q0.w * wxGO[3]  + aGO;
                aIF = q1.x * wxIF[4]  + aIF;  aGO = q1.x * wxGO[4]  + aGO;
                aIF = q1.y * wxIF[5]  + aIF;  aGO = q1.y * wxGO[5]  + aGO;
                aIF = q1.z * wxIF[6]  + aIF;  aGO = q1.z * wxGO[6]  + aGO;
                aIF = q1.w * wxIF[7]  + aIF;  aGO = q1.w * wxGO[7]  + aGO;
                aIF = q2.x * wxIF[8]  + aIF;  aGO = q2.x * wxGO[8]  + aGO;
                aIF = q2.y * wxIF[9]  + aIF;  aGO = q2.y * wxGO[9]  + aGO;
                aIF = q2.z * wxIF[10] + aIF;  aGO = q2.z * wxGO[10] + aGO;
                aIF = q2.w * wxIF[11] + aIF;  aGO = q2.w * wxGO[11] + aGO;
                aIF = q3.x * wxIF[12] + aIF;  aGO = q3.x * wxGO[12] + aGO;
                aIF = q3.y * wxIF[13] + aIF;  aGO = q3.y * wxGO[13] + aGO;
                aIF = q3.z * wxIF[14] + aIF;  aGO = q3.z * wxGO[14] + aGO;
                aIF = q3.w * wxIF[15] + aIF;  aGO = q3.w * wxGO[15] + aGO;
                aIF = bt.x * wxIF[16] + aIF;  aGO = bt.x * wxGO[16] + aGO;
                aIF = bt.y * wxIF[17] + aIF;  aGO = bt.y * wxGO[17] + aGO;
                XG[bf][k][s][j] = v4f{aIF.x, aIF.y, aGO.x, aGO.y};
            }
        };

        // prologue: DMA chunks 0..3 (72 ops); vmcnt(36) -> {0,1} ready
        dma_chunk(0); dma_chunk(1); dma_chunk(2); dma_chunk(3);
        asm volatile("s_waitcnt vmcnt(36)" ::: "memory");
        produce_chunk(0);
        produce_chunk(1);
        asm volatile("s_waitcnt lgkmcnt(0)" ::: "memory");
        __builtin_amdgcn_sched_barrier(0);
        __builtin_amdgcn_s_barrier();
        __builtin_amdgcn_sched_barrier(0);

        for (int I = 0; I < nwin; ++I) {
            dma_chunk(2 * I + 4);
            dma_chunk(2 * I + 5);
            asm volatile("s_waitcnt vmcnt(36)" ::: "memory");
            produce_chunk(2 * I + 2);
            produce_chunk(2 * I + 3);
            asm volatile("s_waitcnt lgkmcnt(0)" ::: "memory");
            __builtin_amdgcn_sched_barrier(0);
            __builtin_amdgcn_s_barrier();
            __builtin_amdgcn_sched_barrier(0);
        }
    } else {
        // ============================ CONSUMER ============================
        const int len = lengths[g * 8 + s];

        // per-lane recurrent weights (natural j order - no calibration)
        v2f whIF[8], whGO[8];
#pragma unroll
        for (int r = 0; r < 8; ++r) {
            whIF[r] = v2f{W_hh[j * 8 + r],        W_hh[(8 + j) * 8 + r]};
            whGO[r] = v2f{W_hh[(16 + j) * 8 + r], W_hh[(24 + j) * 8 + r]};
        }
        float wl[8];
#pragma unroll
        for (int r = 0; r < 8; ++r) wl[r] = W_lin[r];
        const float bl = b_lin[0];

        float* yb = out + (size_t)(g * 8 + s) * NT;

        float h_all[8];
#pragma unroll
        for (int r = 0; r < 8; ++r) h_all[r] = 0.0f;
        float c_ = 0.0f, hown = 0.0f;
        const int lbase = w & 56;       // shfl group base (R1-proven)

        __builtin_amdgcn_s_barrier();   // pairs with producer prologue
        __builtin_amdgcn_sched_barrier(0);

        for (int I = 0; I < nwin; ++I) {
            const int t = I * 16;
            const v4f* xg0 = &XG[(2 * I) & 3][0][s][j];       // step stride 64 v4f
            const v4f* xg1 = &XG[(2 * I + 1) & 3][0][s][j];
            float y[16];
            v4f xgn = xg0[0];   // first read AFTER barrier (writer was last window)
#pragma unroll
            for (int k = 0; k < 16; ++k) {
                const v4f xgc = xgn;
                if (k < 15) xgn = (k + 1 < 8) ? xg0[(k + 1) * 64] : xg1[(k + 1 - 8) * 64];

                // recurrent dots (h_all = h_{t-1}, gathered last step)
                v2f aIF = v2f{xgc.x, xgc.y}, aGO = v2f{xgc.z, xgc.w};
                aIF = h_all[0] * whIF[0] + aIF;  aGO = h_all[0] * whGO[0] + aGO;
                aIF = h_all[1] * whIF[1] + aIF;  aGO = h_all[1] * whGO[1] + aGO;
                aIF = h_all[2] * whIF[2] + aIF;  aGO = h_all[2] * whGO[2] + aGO;
                aIF = h_all[3] * whIF[3] + aIF;  aGO = h_all[3] * whGO[3] + aGO;
                aIF = h_all[4] * whIF[4] + aIF;  aGO = h_all[4] * whGO[4] + aGO;
                aIF = h_all[5] * whIF[5] + aIF;  aGO = h_all[5] * whGO[5] + aGO;
                aIF = h_all[6] * whIF[6] + aIF;  aGO = h_all[6] * whGO[6] + aGO;
                aIF = h_all[7] * whIF[7] + aIF;  aGO = h_all[7] * whGO[7] + aGO;

                // activations (all lane-local): i,f,o sigma; g,c tanh
                const float si = __builtin_amdgcn_rcpf(
                    1.0f + __builtin_amdgcn_exp2f(aIF.x * -LOG2E));
                const float sf = __builtin_amdgcn_rcpf(
                    1.0f + __builtin_amdgcn_exp2f(aIF.y * -LOG2E));
                const float tg = fmaf(2.0f, __builtin_amdgcn_rcpf(
                    1.0f + __builtin_amdgcn_exp2f(aGO.x * (-2.0f * LOG2E))), -1.0f);
                const float so = __builtin_amdgcn_rcpf(
                    1.0f + __builtin_amdgcn_exp2f(aGO.y * -LOG2E));
                c_ = fmaf(sf, c_, si * tg);
                const float tc = fmaf(-2.0f, __builtin_amdgcn_rcpf(
                    1.0f + __builtin_amdgcn_exp2f(c_ * (2.0f * LOG2E))), 1.0f);
                hown = so * tc;

                // gather h_t within the 8-lane group (R1-proven pattern)
                h_all[0] = __shfl(hown, lbase | 0, 64);
                h_all[1] = __shfl(hown, lbase | 1, 64);
                h_all[2] = __shfl(hown, lbase | 2, 64);
                h_all[3] = __shfl(hown, lbase | 3, 64);
                h_all[4] = __shfl(hown, lbase | 4, 64);
                h_all[5] = __shfl(hown, lbase | 5, 64);
                h_all[6] = __shfl(hown, lbase | 6, 64);
                h_all[7] = __shfl(hown, lbase | 7, 64);

                // linear head on h_t (off the recurrence chain)
                float yv = bl;
                yv = fmaf(h_all[0], wl[0], yv);
                yv = fmaf(h_all[1], wl[1], yv);
                yv = fmaf(h_all[2], wl[2], yv);
                yv = fmaf(h_all[3], wl[3], yv);
                yv = fmaf(h_all[4], wl[4], yv);
                yv = fmaf(h_all[5], wl[5], yv);
                yv = fmaf(h_all[6], wl[6], yv);
                yv = fmaf(h_all[7], wl[7], yv);
                y[k] = yv;
            }

            if (j == 0) {
                if (t + 15 < len) {
                    *(v4f*)(yb + t)      = v4f{y[0],  y[1],  y[2],  y[3]};
                    *(v4f*)(yb + t + 4)  = v4f{y[4],  y[5],  y[6],  y[7]};
                    *(v4f*)(yb + t + 8)  = v4f{y[8],  y[9],  y[10], y[11]};
                    *(v4f*)(yb + t + 12) = v4f{y[12], y[13], y[14], y[15]};
                } else {
#pragma unroll
                    for (int k = 0; k < 16; ++k)
                        if (t + k < len) yb[t + k] = y[k];
                }
            }
            __builtin_amdgcn_sched_barrier(0);
            __builtin_amdgcn_s_barrier();
            __builtin_amdgcn_sched_barrier(0);
        }
    }
}

} // namespace

extern "C" void kernel_launch(void* const* d_in, const int* in_sizes, int n_in,
                              void* d_out, int out_size, void* d_ws, size_t ws_size,
                              hipStream_t stream) {
    const float* x     = (const float*)d_in[0];
    const int*   lens  = (const int*)d_in[1];
    const float* W_ih  = (const float*)d_in[2];
    const float* W_hh  = (const float*)d_in[3];
    const float* b_ih  = (const float*)d_in[4];
    const float* b_hh  = (const float*)d_in[5];
    const float* W_lin = (const float*)d_in[6];
    const float* b_lin = (const float*)d_in[7];
    float* out = (float*)d_out;

    // zero the padded region (kernel only writes t < len)
    hipMemsetAsync(out, 0, (size_t)4096 * NT * sizeof(float), stream);

    lstm_pc8<<<512, 128, 0, stream>>>(x, lens, W_ih, W_hh, b_ih, b_hh,
                                      W_lin, b_lin, out);
}

// Round 17
// 76.873 us; speedup vs baseline: 1.3718x; 1.3718x over previous
//
#include <hip/hip_runtime.h>

// Packed-sequence LSTM (B=4096, T=512, D=18, H=8) + Linear(8->1) head.
//
// R17 = R14 (best: 75.9us; 16-step windows, producer/consumer wave split,
// 16-lane DPP consumer, length-balanced swizzle) + ONE delta:
//   all v2f dot products go through __builtin_elementwise_fma
//   (llvm.fma.v2f32 -> v_pk_fma_f32 via isel: packed math WITHOUT the
//   inline-asm copies that sank R11/R13).
// Model: SIMDs are issue-saturated (4 blocks/CU x 2 waves = ~6300cy issue
// per 5700cy window per SIMD; VALUBusy ~40% per wave ~= 100% per SIMD).
// If the compiler was scalarizing the v2f expressions (R6 issue-count
// evidence), this halves FMA issue on both waves; if it already packed,
// this is a numerical no-op (fma contraction was already on).
// Consumer chains additionally seed xg into the first FMA's addend
// (removes 2 serial adds from the recurrence chain).
// R16 lesson (reverted): __shfl h-gather = ds_bpermute = DS-pipe latency
// on the serial chain; DPP-only cross-lane is mandatory.

namespace {

constexpr int NT = 512;
constexpr int ND = 18;
constexpr float LOG2E = 1.4426950408889634f;

typedef float v2f __attribute__((ext_vector_type(2)));
typedef float v4f __attribute__((ext_vector_type(4)));

template <int C>
__device__ __forceinline__ float fdpp(float v) {
    const int i = __float_as_int(v);
    return __int_as_float(__builtin_amdgcn_update_dpp(i, i, C, 0xF, 0xF, true));
}
__device__ __forceinline__ void gload_lds(const void* g, void* l) {
    __builtin_amdgcn_global_load_lds(
        (const __attribute__((address_space(1))) void*)g,
        (__attribute__((address_space(3))) void*)l, 4, 0, 0);
}
__device__ __forceinline__ v2f vfma(v2f a, v2f b, v2f c) {
    return __builtin_elementwise_fma(a, b, c);
}

__global__ __launch_bounds__(128, 1) void lstm_pc(
    const float* __restrict__ x, const int* __restrict__ lengths,
    const float* __restrict__ W_ih, const float* __restrict__ W_hh,
    const float* __restrict__ b_ih, const float* __restrict__ b_hh,
    const float* __restrict__ W_lin, const float* __restrict__ b_lin,
    float* __restrict__ out)
{
    // A ring: 32 row slots (row r -> slot r&31), [seq][elem0..15].
    // B ring: 4 chunk blocks, [row-in-chunk][seq][elem16..17].
    // XG ring: 4 chunk buffers, [t-in-chunk][gate-pair][seq(+1 pad)] of v2f.
    __shared__ __align__(16) float Aring[32][4][16];
    __shared__ __align__(16) float Bring[4][8][4][2];
    __shared__ __align__(16) v2f   XG[4][8][16][5];

    // Length-balanced swizzle: CU hosting round-slot q gets groups
    // {q, 1023-q, 256+q, 767-q} -> per-CU work ~constant (~1024 step-units).
    const int q_ = (int)blockIdx.x & 255;
    const int r_ = (int)blockIdx.x >> 8;
    const int g  = (r_ == 0) ? q_ : (r_ == 1) ? (1023 - q_)
                 : (r_ == 2) ? (256 + q_) : (767 - q_);

    const int tid  = (int)threadIdx.x;
    const int wav  = tid >> 6;          // 0 = consumer, 1 = producer
    const int w    = tid & 63;
    const int grp  = w >> 4;            // seq within block
    const int l16  = w & 15;
    const int p    = l16 >> 3;          // half: 0 -> {i,g}, 1 -> {f,o}
    const int j    = l16 & 7;           // hidden unit
    const int lenmax = lengths[g * 4];  // sorted desc -> block max
    const int nwin = (lenmax + 15) >> 4;              // 16-step windows
    const int rowA = j + (p ? 8 : 0);   // p0: i, p1: f
    const int rowB = j + (p ? 24 : 16); // p0: g, p1: o

    if (wav == 1) {
        // ============================ PRODUCER ============================
        v2f wxA[9], wxB[9];
        {
            const v2f* ra = (const v2f*)(W_ih + rowA * ND);
            const v2f* rb = (const v2f*)(W_ih + rowB * ND);
#pragma unroll
            for (int k = 0; k < 9; ++k) { wxA[k] = ra[k]; wxB[k] = rb[k]; }
        }
        const float biasA = b_ih[rowA] + b_hh[rowA];
        const float biasB = b_ih[rowB] + b_hh[rowB];

        // DMA source lanes: A-op: seq w>>4, elem w&15 (row uniform).
        // B-op: row w>>3, seq (w>>1)&3, elem 16+(w&1); dest linear = lane.
        const char* xc = (const char*)x;
        const char* pA = xc + (size_t)((((unsigned)(g * 4 + (w >> 4)) * (NT * ND))
                                       + (unsigned)(w & 15)) * 4u);
        const char* pB = xc + (size_t)((((unsigned)(g * 4 + ((w >> 1) & 3)) * (NT * ND))
                                       + 16u + (unsigned)(w & 1)) * 4u);
        const unsigned rB0 = (unsigned)(w >> 3);

        auto dma_chunk = [&](int dd) {
            const int r0 = dd * 8;
#pragma unroll
            for (int k = 0; k < 8; ++k) {
                const int rr = (r0 + k < NT) ? (r0 + k) : (NT - 1);
                gload_lds(pA + (unsigned)rr * 72u, &Aring[(r0 + k) & 31][0][0]);
            }
            unsigned rb = (unsigned)r0 + rB0;
            rb = (rb < (unsigned)NT) ? rb : (unsigned)(NT - 1);
            gload_lds(pB + rb * 72u, &Bring[dd & 3][0][0][0]);
        };

        // produce: packed fma via llvm.fma.v2f32; compiler-scheduled loads
        auto produce_chunk = [&](int cc) {
            const int s0 = (cc * 8) & 31;
            const int bf = cc & 3;
#pragma unroll
            for (int k = 0; k < 8; ++k) {
                const v4f* ap = (const v4f*)&Aring[s0 + k][grp][0];
                const v4f q0 = ap[0], q1 = ap[1], q2 = ap[2], q3 = ap[3];
                const v2f bt = *(const v2f*)&Bring[bf][k][grp][0];
                v2f aA = vfma(q0.lo, wxA[0], v2f{biasA, 0.f});
                v2f aB = vfma(q0.lo, wxB[0], v2f{biasB, 0.f});
                aA = vfma(q0.hi, wxA[1], aA);  aB = vfma(q0.hi, wxB[1], aB);
                aA = vfma(q1.lo, wxA[2], aA);  aB = vfma(q1.lo, wxB[2], aB);
                aA = vfma(q1.hi, wxA[3], aA);  aB = vfma(q1.hi, wxB[3], aB);
                aA = vfma(q2.lo, wxA[4], aA);  aB = vfma(q2.lo, wxB[4], aB);
                aA = vfma(q2.hi, wxA[5], aA);  aB = vfma(q2.hi, wxB[5], aB);
                aA = vfma(q3.lo, wxA[6], aA);  aB = vfma(q3.lo, wxB[6], aB);
                aA = vfma(q3.hi, wxA[7], aA);  aB = vfma(q3.hi, wxB[7], aB);
                aA = vfma(bt,    wxA[8], aA);  aB = vfma(bt,    wxB[8], aB);
                XG[bf][k][l16][grp] = v2f{aA.x + aA.y, aB.x + aB.y};
            }
        };

        // prologue: DMA chunks 0..3 (36 ops); {0,1} ready after vmcnt(18)
        dma_chunk(0); dma_chunk(1); dma_chunk(2); dma_chunk(3);
        asm volatile("s_waitcnt vmcnt(18)" ::: "memory");
        produce_chunk(0);
        produce_chunk(1);
        asm volatile("s_waitcnt lgkmcnt(0)" ::: "memory");
        __builtin_amdgcn_sched_barrier(0);
        __builtin_amdgcn_s_barrier();
        __builtin_amdgcn_sched_barrier(0);

        for (int I = 0; I < nwin; ++I) {
            dma_chunk(2 * I + 4);
            dma_chunk(2 * I + 5);
            asm volatile("s_waitcnt vmcnt(18)" ::: "memory");
            produce_chunk(2 * I + 2);
            produce_chunk(2 * I + 3);
            asm volatile("s_waitcnt lgkmcnt(0)" ::: "memory");
            __builtin_amdgcn_sched_barrier(0);
            __builtin_amdgcn_s_barrier();
            __builtin_amdgcn_sched_barrier(0);
        }
    } else {
        // ============================ CONSUMER ============================
        const int len = lengths[g * 4 + grp];

        // DPP self-calibration: which h-index does row_ror:r deliver here?
        int idx[8];
        idx[0] = j;
        idx[1] = __builtin_amdgcn_update_dpp(0, j, 0x121, 0xF, 0xF, true) & 7;
        idx[2] = __builtin_amdgcn_update_dpp(0, j, 0x122, 0xF, 0xF, true) & 7;
        idx[3] = __builtin_amdgcn_update_dpp(0, j, 0x123, 0xF, 0xF, true) & 7;
        idx[4] = __builtin_amdgcn_update_dpp(0, j, 0x124, 0xF, 0xF, true) & 7;
        idx[5] = __builtin_amdgcn_update_dpp(0, j, 0x125, 0xF, 0xF, true) & 7;
        idx[6] = __builtin_amdgcn_update_dpp(0, j, 0x126, 0xF, 0xF, true) & 7;
        idx[7] = __builtin_amdgcn_update_dpp(0, j, 0x127, 0xF, 0xF, true) & 7;

        v2f whA[4], whB[4], wl2[4];
#pragma unroll
        for (int r = 0; r < 4; ++r) {
            whA[r] = v2f{W_hh[rowA * 8 + idx[2 * r]], W_hh[rowA * 8 + idx[2 * r + 1]]};
            whB[r] = v2f{W_hh[rowB * 8 + idx[2 * r]], W_hh[rowB * 8 + idx[2 * r + 1]]};
            wl2[r] = v2f{W_lin[idx[2 * r]], W_lin[idx[2 * r + 1]]};
        }
        const float bl = b_lin[0];
        // vB exponent scale: p0 computes tanh(g)=2*sigma(2g)-1, p1 sigma(o)
        const float Kp = p ? -LOG2E : -2.0f * LOG2E;

        float* yb = out + (size_t)(g * 4 + grp) * NT;

        v2f hp[4] = {v2f{0.f, 0.f}, v2f{0.f, 0.f}, v2f{0.f, 0.f}, v2f{0.f, 0.f}};
        float c_ = 0.0f, hown = 0.0f;

        __builtin_amdgcn_s_barrier();           // pairs with producer prologue
        __builtin_amdgcn_sched_barrier(0);

        for (int I = 0; I < nwin; ++I) {
            const int t = I * 16;
            const v2f* xg0 = &XG[(2 * I) & 3][0][l16][grp];      // step stride 80 v2f
            const v2f* xg1 = &XG[(2 * I + 1) & 3][0][l16][grp];
            float y[16];
            v2f xgn = xg0[0];   // first read AFTER barrier (writer was last window)
#pragma unroll
            for (int k = 0; k < 16; ++k) {
                const v2f xgc = xgn;
                if (k < 15) xgn = (k + 1 < 8) ? xg0[(k + 1) * 80] : xg1[(k + 1 - 8) * 80];

                // recurrent dots (packed; xg seeded into the chain head)
                v2f tA = vfma(hp[0], whA[0], v2f{xgc.x, 0.f});
                tA = vfma(hp[1], whA[1], tA);
                tA = vfma(hp[2], whA[2], tA);
                tA = vfma(hp[3], whA[3], tA);
                v2f tB = vfma(hp[0], whB[0], v2f{xgc.y, 0.f});
                tB = vfma(hp[1], whB[1], tB);
                tB = vfma(hp[2], whB[2], tB);
                tB = vfma(hp[3], whB[3], tB);
                const float aA = tA.x + tA.y;
                const float aB = tB.x + tB.y;

                // activations: vA = sigma(i|f); vB = p0 tanh(g), p1 sigma(o)
                const float vA = __builtin_amdgcn_rcpf(
                    1.0f + __builtin_amdgcn_exp2f(aA * -LOG2E));
                const float sB = __builtin_amdgcn_rcpf(
                    1.0f + __builtin_amdgcn_exp2f(aB * Kp));
                const float vB = p ? sB : fmaf(2.0f, sB, -1.0f);

                // half exchange via ror:8; unmasked cell update
                const float send1 = p ? vA : (vA * vB);
                const float ex1 = fdpp<0x128>(send1);
                const float f_ = p ? send1 : ex1;
                const float ig_ = p ? ex1 : send1;
                c_ = fmaf(f_, c_, ig_);
                const float tc = fmaf(-2.0f, __builtin_amdgcn_rcpf(
                    1.0f + __builtin_amdgcn_exp2f(c_ * (2.0f * LOG2E))), 1.0f);
                const float ex2 = fdpp<0x128>(vB);
                const float o_ = p ? vB : ex2;
                hown = o_ * tc;

                // h rotations -> pairs
                const float h1 = fdpp<0x121>(hown);
                const float h2 = fdpp<0x122>(hown);
                const float h3 = fdpp<0x123>(hown);
                const float h4 = fdpp<0x124>(hown);
                const float h5 = fdpp<0x125>(hown);
                const float h6 = fdpp<0x126>(hown);
                const float h7 = fdpp<0x127>(hown);
                hp[0] = v2f{hown, h1}; hp[1] = v2f{h2, h3};
                hp[2] = v2f{h4, h5};   hp[3] = v2f{h6, h7};

                // linear head (off the critical chain; packed)
                v2f ya = vfma(hp[0], wl2[0], v2f{bl, 0.f});
                ya = vfma(hp[1], wl2[1], ya);
                ya = vfma(hp[2], wl2[2], ya);
                ya = vfma(hp[3], wl2[3], ya);
                y[k] = ya.x + ya.y;
            }

            if (l16 == 0) {
                if (t + 15 < len) {
                    *(v4f*)(yb + t)      = v4f{y[0],  y[1],  y[2],  y[3]};
                    *(v4f*)(yb + t + 4)  = v4f{y[4],  y[5],  y[6],  y[7]};
                    *(v4f*)(yb + t + 8)  = v4f{y[8],  y[9],  y[10], y[11]};
                    *(v4f*)(yb + t + 12) = v4f{y[12], y[13], y[14], y[15]};
                } else {
#pragma unroll
                    for (int k = 0; k < 16; ++k)
                        if (t + k < len) yb[t + k] = y[k];
                }
            }
            __builtin_amdgcn_sched_barrier(0);
            __builtin_amdgcn_s_barrier();
            __builtin_amdgcn_sched_barrier(0);
        }
    }
}

} // namespace

extern "C" void kernel_launch(void* const* d_in, const int* in_sizes, int n_in,
                              void* d_out, int out_size, void* d_ws, size_t ws_size,
                              hipStream_t stream) {
    const float* x     = (const float*)d_in[0];
    const int*   lens  = (const int*)d_in[1];
    const float* W_ih  = (const float*)d_in[2];
    const float* W_hh  = (const float*)d_in[3];
    const float* b_ih  = (const float*)d_in[4];
    const float* b_hh  = (const float*)d_in[5];
    const float* W_lin = (const float*)d_in[6];
    const float* b_lin = (const float*)d_in[7];
    float* out = (float*)d_out;

    // zero the padded region (kernel only writes t < len)
    hipMemsetAsync(out, 0, (size_t)4096 * NT * sizeof(float), stream);

    lstm_pc<<<1024, 128, 0, stream>>>(x, lens, W_ih, W_hh, b_ih, b_hh,
                                      W_lin, b_lin, out);
}